// Round 1
// baseline (620.452 us; speedup 1.0000x reference)
//
#include <hip/hip_runtime.h>
#include <math.h>

#define N    512
#define CS   384
#define CZ   128
#define H    12
#define D    16
#define PQ   4
#define PV   8
#define CAT_W 2112

#define WC 0.23570226039551584f  /* sqrt(2/(9*4)) */
#define WL 0.5773502691896258f   /* sqrt(1/3) */

// workspace offsets (in floats)
#define O_Q    0          /* 512*192  */
#define O_K    98304
#define O_V    196608
#define O_QF   294912     /* raw local points 512*144 */
#define O_KF   368640
#define O_VF   442368     /* 512*288 */
#define O_GQ   589824     /* global-frame points 512*144 */
#define O_GK   663552
#define O_GV   737280     /* 512*288 */
#define O_BIAS 884736     /* 512*512*12 */
#define O_CAT  4030464    /* 512*2112 */
/* total 5,111,808 floats = 20.4 MB */

// ---------------- projections: s @ {w_q,w_k,w_v,w_qf,w_kf,w_vf} ----------------
__global__ __launch_bounds__(256) void k_proj(
    const float* __restrict__ s,
    const float* __restrict__ wq, const float* __restrict__ wk,
    const float* __restrict__ wv, const float* __restrict__ wqf,
    const float* __restrict__ wkf, const float* __restrict__ wvf,
    float* __restrict__ ws) {
  int id = blockIdx.x * 256 + threadIdx.x;           // 512*1152 total
  int i = id / 1152, p = id % 1152;
  const float* w; int col, W; float* dst;
  if (p < 192)      { w = wq;  col = p;     W = 192; dst = ws + O_Q  + i*192 + col; }
  else if (p < 384) { w = wk;  col = p-192; W = 192; dst = ws + O_K  + i*192 + col; }
  else if (p < 576) { w = wv;  col = p-384; W = 192; dst = ws + O_V  + i*192 + col; }
  else if (p < 720) { w = wqf; col = p-576; W = 144; dst = ws + O_QF + i*144 + col; }
  else if (p < 864) { w = wkf; col = p-720; W = 144; dst = ws + O_KF + i*144 + col; }
  else              { w = wvf; col = p-864; W = 288; dst = ws + O_VF + i*288 + col; }
  const float* srow = s + i*CS;
  float acc = 0.f;
  for (int k = 0; k < CS; ++k) acc += srow[k] * w[k*W + col];
  *dst = acc;
}

// ---------------- lift local points to global frame ----------------
__global__ __launch_bounds__(256) void k_lift(
    const float* __restrict__ rot, const float* __restrict__ trans,
    float* __restrict__ ws) {
  int id = blockIdx.x * 256 + threadIdx.x;           // 512*192 points
  int i = id / 192, pt = id % 192;
  const float* src; float* dst;
  if (pt < 48)      { src = ws + O_QF + i*144 + pt*3;      dst = ws + O_GQ + i*144 + pt*3; }
  else if (pt < 96) { src = ws + O_KF + i*144 + (pt-48)*3; dst = ws + O_GK + i*144 + (pt-48)*3; }
  else              { src = ws + O_VF + i*288 + (pt-96)*3; dst = ws + O_GV + i*288 + (pt-96)*3; }
  float l0 = src[0], l1 = src[1], l2 = src[2];
  const float* R = rot + i*9;
  const float* T = trans + i*3;
  #pragma unroll
  for (int o = 0; o < 3; ++o)
    dst[o] = R[o*3+0]*l0 + R[o*3+1]*l1 + R[o*3+2]*l2 + T[o];
}

// ---------------- bias[i,j,h] = z[i,j,:] . w_bias[:,h] ----------------
__global__ __launch_bounds__(256) void k_bias(
    const float* __restrict__ z, const float* __restrict__ wb,
    float* __restrict__ ws) {
  __shared__ float wbl[CZ*H];
  int t = threadIdx.x;
  for (int idx = t; idx < CZ*H; idx += 256) wbl[idx] = wb[idx];
  __syncthreads();
  int id = blockIdx.x * 256 + t;                     // 512*512 threads
  int i = id / N, j = id % N;
  const float4* zr = (const float4*)(z + (size_t)(i*N + j) * CZ);
  float acc[H];
  #pragma unroll
  for (int h = 0; h < H; ++h) acc[h] = 0.f;
  for (int k4 = 0; k4 < CZ/4; ++k4) {
    float4 v = zr[k4];
    int c = k4*4;
    #pragma unroll
    for (int h = 0; h < H; ++h)
      acc[h] += v.x*wbl[(c+0)*H+h] + v.y*wbl[(c+1)*H+h]
              + v.z*wbl[(c+2)*H+h] + v.w*wbl[(c+3)*H+h];
  }
  float* dst = ws + O_BIAS + (size_t)(i*N + j) * H;
  #pragma unroll
  for (int h = 0; h < H; ++h) dst[h] = acc[h];
}

// ---------------- fused attention per row i ----------------
__global__ __launch_bounds__(256) void k_attn(
    const float* __restrict__ z, const float* __restrict__ rot,
    const float* __restrict__ trans, const float* __restrict__ hw,
    float* __restrict__ ws) {
  __shared__ float sc[N*H];       // 6144 floats = 24 KB: scores -> attn
  __shared__ float Qi[H*D];
  __shared__ float gqi[H*PQ*3];
  __shared__ float tmpP[H*PV*3];
  __shared__ float coef[H];
  int i = blockIdx.x;
  int t = threadIdx.x;

  if (t < 192) Qi[t]  = ws[O_Q  + (size_t)i*192 + t];
  if (t < 144) gqi[t] = ws[O_GQ + (size_t)i*144 + t];
  if (t < H) {
    float x = hw[t];
    float sp = fmaxf(x, 0.f) + log1pf(__expf(-fabsf(x)));  // softplus
    coef[t] = -0.5f * WC * sp;
  }
  __syncthreads();

  // phase 1: scores
  const float* Kg   = ws + O_K;
  const float* gk   = ws + O_GK;
  const float* bias = ws + O_BIAS + (size_t)i*N*H;
  for (int task = t; task < N*H; task += 256) {
    int j = task / H, h = task % H;
    const float* Kr = Kg + j*192 + h*16;
    const float* Qr = Qi + h*16;
    float rep = 0.f;
    #pragma unroll
    for (int d = 0; d < 16; ++d) rep += Qr[d] * Kr[d];
    rep = rep * 0.25f + bias[j*H + h];
    const float* gkr = gk + j*144 + h*12;
    const float* gqr = gqi + h*12;
    float pt = 0.f;
    #pragma unroll
    for (int r = 0; r < 12; ++r) { float d = gqr[r] - gkr[r]; pt += d*d; }
    sc[j*H + h] = WL * (rep + coef[h]*pt);
  }
  __syncthreads();

  // phase 2: softmax over j (wave per head-group)
  int wv = t >> 6, lane = t & 63;
  for (int h = wv; h < H; h += 4) {
    float m = -1e30f;
    for (int j = lane; j < N; j += 64) m = fmaxf(m, sc[j*H+h]);
    #pragma unroll
    for (int off = 32; off; off >>= 1) m = fmaxf(m, __shfl_xor(m, off));
    float e = 0.f;
    for (int j = lane; j < N; j += 64) {
      float v = __expf(sc[j*H+h] - m);
      sc[j*H+h] = v; e += v;
    }
    #pragma unroll
    for (int off = 32; off; off >>= 1) e += __shfl_xor(e, off);
    float inv = 1.f / e;
    for (int j = lane; j < N; j += 64) sc[j*H+h] *= inv;
  }
  __syncthreads();

  // phase 3: out_rep (-> cat[0:192]) and tmp points (-> LDS)
  float* cat = ws + O_CAT + (size_t)i*CAT_W;
  const float* Vg  = ws + O_V;
  const float* gvv = ws + O_GV;
  for (int task = t; task < 480; task += 256) {
    if (task < 192) {
      int h = task >> 4;
      float acc = 0.f;
      for (int j = 0; j < N; ++j) acc += sc[j*H+h] * Vg[j*192 + task];
      cat[task] = acc;
    } else {
      int u = task - 192;          // u = h*24 + q*3 + o
      int h = u / 24;
      float acc = 0.f;
      for (int j = 0; j < N; ++j) acc += sc[j*H+h] * gvv[j*288 + u];
      tmpP[u] = acc;
    }
  }

  // phase 4: out_pair -> cat[576 + h*128 + c]
  {
    int g = t >> 7, c = t & 127;   // g selects even/odd heads
    float acc[6];
    #pragma unroll
    for (int k = 0; k < 6; ++k) acc[k] = 0.f;
    const float* zr = z + (size_t)i*N*CZ + c;
    for (int j = 0; j < N; ++j) {
      float zv = zr[(size_t)j*CZ];
      #pragma unroll
      for (int k = 0; k < 6; ++k) acc[k] += sc[j*H + (k*2+g)] * zv;
    }
    #pragma unroll
    for (int k = 0; k < 6; ++k) cat[576 + (k*2+g)*128 + c] = acc[k];
  }
  __syncthreads();

  // phase 5: frame-inverse + norms
  if (t < 96) {
    int h = t >> 3, q = t & 7;
    const float* R = rot + i*9;
    float tp[3];
    #pragma unroll
    for (int p = 0; p < 3; ++p) tp[p] = tmpP[h*24 + q*3 + p] - trans[i*3 + p];
    float nrm = 1e-8f;
    #pragma unroll
    for (int o = 0; o < 3; ++o) {
      // out_vals[o] = sum_p R[p,o] * (tmp[p] - t[p])
      float v = R[o]*tp[0] + R[3+o]*tp[1] + R[6+o]*tp[2];
      cat[192 + h*24 + q*3 + o] = v;
      nrm += v*v;
    }
    cat[480 + h*8 + q] = sqrtf(nrm);
  }
}

// ---------------- final GEMM: cat @ w_out + b_out ----------------
__global__ __launch_bounds__(128) void k_out(
    const float* __restrict__ wo, const float* __restrict__ bo,
    const float* __restrict__ ws, float* __restrict__ out) {
  int c  = blockIdx.y * 128 + threadIdx.x;  // 0..383
  int i0 = blockIdx.x * 8;                  // 8 rows per block
  float b = bo[c];
  float acc[8];
  #pragma unroll
  for (int r = 0; r < 8; ++r) acc[r] = b;
  const float* cat = ws + O_CAT + (size_t)i0 * CAT_W;
  for (int k = 0; k < CAT_W; ++k) {
    float wv = wo[(size_t)k*384 + c];
    #pragma unroll
    for (int r = 0; r < 8; ++r) acc[r] += cat[r*CAT_W + k] * wv;
  }
  #pragma unroll
  for (int r = 0; r < 8; ++r) out[(i0 + r)*384 + c] = acc[r];
}

extern "C" void kernel_launch(void* const* d_in, const int* in_sizes, int n_in,
                              void* d_out, int out_size, void* d_ws, size_t ws_size,
                              hipStream_t stream) {
  const float* s     = (const float*)d_in[0];
  const float* z     = (const float*)d_in[1];
  const float* rot   = (const float*)d_in[2];
  const float* trans = (const float*)d_in[3];
  const float* wq    = (const float*)d_in[4];
  const float* wk    = (const float*)d_in[5];
  const float* wv    = (const float*)d_in[6];
  const float* wqf   = (const float*)d_in[7];
  const float* wkf   = (const float*)d_in[8];
  const float* wvf   = (const float*)d_in[9];
  const float* wb    = (const float*)d_in[10];
  const float* hw    = (const float*)d_in[11];
  const float* wo    = (const float*)d_in[12];
  const float* bo    = (const float*)d_in[13];
  float* out = (float*)d_out;
  float* ws  = (float*)d_ws;

  hipLaunchKernelGGL(k_proj, dim3(512*1152/256), dim3(256), 0, stream,
                     s, wq, wk, wv, wqf, wkf, wvf, ws);
  hipLaunchKernelGGL(k_lift, dim3(512*192/256), dim3(256), 0, stream,
                     rot, trans, ws);
  hipLaunchKernelGGL(k_bias, dim3(512*512/256), dim3(256), 0, stream,
                     z, wb, ws);
  hipLaunchKernelGGL(k_attn, dim3(512), dim3(256), 0, stream,
                     z, rot, trans, hw, ws);
  hipLaunchKernelGGL(k_out, dim3(64, 3), dim3(128), 0, stream,
                     wo, bo, ws, out);
}

// Round 2
// 470.052 us; speedup vs baseline: 1.3200x; 1.3200x over previous
//
#include <hip/hip_runtime.h>
#include <math.h>

#define N    512
#define CS   384
#define CZ   128
#define H    12
#define D    16
#define PQ   4
#define PV   8
#define CAT_W 2112

#define WC 0.23570226039551584f  /* sqrt(2/(9*4)) */
#define WL 0.5773502691896258f   /* sqrt(1/3) */

// workspace offsets (in floats)
#define O_Q    0          /* 512*192  */
#define O_K    98304
#define O_V    196608
#define O_QF   294912     /* raw local points 512*144 */
#define O_KF   368640
#define O_VF   442368     /* 512*288 */
#define O_GQ   589824     /* global-frame points 512*144 */
#define O_GK   663552
#define O_GV   737280     /* 512*288 */
#define O_BIAS 884736     /* 512*512*12 = 3145728 floats; reused as k_out partials after k_attn */
#define O_PART O_BIAS     /* 8 * 196608 = 1572864 floats, fits in bias region */
#define O_CAT  4030464    /* 512*2112 */
/* total 5,111,808 floats = 20.4 MB */

#define KSPLIT 8
#define KCH    264        /* 2112 / 8 */

// ---------------- projections: s @ {w_q,w_k,w_v,w_qf,w_kf,w_vf} ----------------
__global__ __launch_bounds__(256) void k_proj(
    const float* __restrict__ s,
    const float* __restrict__ wq, const float* __restrict__ wk,
    const float* __restrict__ wv, const float* __restrict__ wqf,
    const float* __restrict__ wkf, const float* __restrict__ wvf,
    float* __restrict__ ws) {
  int id = blockIdx.x * 256 + threadIdx.x;           // 512*1152 total
  int i = id / 1152, p = id % 1152;
  const float* w; int col, W; float* dst;
  if (p < 192)      { w = wq;  col = p;     W = 192; dst = ws + O_Q  + i*192 + col; }
  else if (p < 384) { w = wk;  col = p-192; W = 192; dst = ws + O_K  + i*192 + col; }
  else if (p < 576) { w = wv;  col = p-384; W = 192; dst = ws + O_V  + i*192 + col; }
  else if (p < 720) { w = wqf; col = p-576; W = 144; dst = ws + O_QF + i*144 + col; }
  else if (p < 864) { w = wkf; col = p-720; W = 144; dst = ws + O_KF + i*144 + col; }
  else              { w = wvf; col = p-864; W = 288; dst = ws + O_VF + i*288 + col; }
  const float* srow = s + i*CS;
  float acc = 0.f;
  #pragma unroll 8
  for (int k = 0; k < CS; ++k) acc += srow[k] * w[k*W + col];
  *dst = acc;
}

// ---------------- lift local points to global frame ----------------
__global__ __launch_bounds__(256) void k_lift(
    const float* __restrict__ rot, const float* __restrict__ trans,
    float* __restrict__ ws) {
  int id = blockIdx.x * 256 + threadIdx.x;           // 512*192 points
  int i = id / 192, pt = id % 192;
  const float* src; float* dst;
  if (pt < 48)      { src = ws + O_QF + i*144 + pt*3;      dst = ws + O_GQ + i*144 + pt*3; }
  else if (pt < 96) { src = ws + O_KF + i*144 + (pt-48)*3; dst = ws + O_GK + i*144 + (pt-48)*3; }
  else              { src = ws + O_VF + i*288 + (pt-96)*3; dst = ws + O_GV + i*288 + (pt-96)*3; }
  float l0 = src[0], l1 = src[1], l2 = src[2];
  const float* R = rot + i*9;
  const float* T = trans + i*3;
  #pragma unroll
  for (int o = 0; o < 3; ++o)
    dst[o] = R[o*3+0]*l0 + R[o*3+1]*l1 + R[o*3+2]*l2 + T[o];
}

// ---------------- bias[i,j,h] = z[i,j,:] . w_bias[:,h] ----------------
__global__ __launch_bounds__(256) void k_bias(
    const float* __restrict__ z, const float* __restrict__ wb,
    float* __restrict__ ws) {
  __shared__ float wbl[CZ*H];
  int t = threadIdx.x;
  for (int idx = t; idx < CZ*H; idx += 256) wbl[idx] = wb[idx];
  __syncthreads();
  int id = blockIdx.x * 256 + t;                     // 512*512 threads
  int i = id / N, j = id % N;
  const float4* zr = (const float4*)(z + (size_t)(i*N + j) * CZ);
  float acc[H];
  #pragma unroll
  for (int h = 0; h < H; ++h) acc[h] = 0.f;
  #pragma unroll 4
  for (int k4 = 0; k4 < CZ/4; ++k4) {
    float4 v = zr[k4];
    int c = k4*4;
    #pragma unroll
    for (int h = 0; h < H; ++h)
      acc[h] += v.x*wbl[(c+0)*H+h] + v.y*wbl[(c+1)*H+h]
              + v.z*wbl[(c+2)*H+h] + v.w*wbl[(c+3)*H+h];
  }
  float* dst = ws + O_BIAS + (size_t)(i*N + j) * H;
  #pragma unroll
  for (int h = 0; h < H; ++h) dst[h] = acc[h];
}

// ---------------- fused attention per row i ----------------
__global__ __launch_bounds__(256) void k_attn(
    const float* __restrict__ z, const float* __restrict__ rot,
    const float* __restrict__ trans, const float* __restrict__ hw,
    float* __restrict__ ws) {
  __shared__ float sc[N*H];       // 6144 floats = 24 KB: scores -> attn
  __shared__ float Qi[H*D];
  __shared__ float gqi[H*PQ*3];
  __shared__ float tmpP[H*PV*3];
  __shared__ float coef[H];
  int i = blockIdx.x;
  int t = threadIdx.x;

  if (t < 192) Qi[t]  = ws[O_Q  + (size_t)i*192 + t];
  if (t < 144) gqi[t] = ws[O_GQ + (size_t)i*144 + t];
  if (t < H) {
    float x = hw[t];
    float sp = fmaxf(x, 0.f) + log1pf(__expf(-fabsf(x)));  // softplus
    coef[t] = -0.5f * WC * sp;
  }
  __syncthreads();

  // phase 1: scores
  const float* Kg   = ws + O_K;
  const float* gk   = ws + O_GK;
  const float* bias = ws + O_BIAS + (size_t)i*N*H;
  for (int task = t; task < N*H; task += 256) {
    int j = task / H, h = task % H;
    const float* Kr = Kg + j*192 + h*16;
    const float* Qr = Qi + h*16;
    float rep = 0.f;
    #pragma unroll
    for (int d = 0; d < 16; ++d) rep += Qr[d] * Kr[d];
    rep = rep * 0.25f + bias[j*H + h];
    const float* gkr = gk + j*144 + h*12;
    const float* gqr = gqi + h*12;
    float pt = 0.f;
    #pragma unroll
    for (int r = 0; r < 12; ++r) { float d = gqr[r] - gkr[r]; pt += d*d; }
    sc[j*H + h] = WL * (rep + coef[h]*pt);
  }
  __syncthreads();

  // phase 2: softmax over j (wave per head-group)
  int wv = t >> 6, lane = t & 63;
  for (int h = wv; h < H; h += 4) {
    float m = -1e30f;
    for (int j = lane; j < N; j += 64) m = fmaxf(m, sc[j*H+h]);
    #pragma unroll
    for (int off = 32; off; off >>= 1) m = fmaxf(m, __shfl_xor(m, off));
    float e = 0.f;
    for (int j = lane; j < N; j += 64) {
      float v = __expf(sc[j*H+h] - m);
      sc[j*H+h] = v; e += v;
    }
    #pragma unroll
    for (int off = 32; off; off >>= 1) e += __shfl_xor(e, off);
    float inv = 1.f / e;
    for (int j = lane; j < N; j += 64) sc[j*H+h] *= inv;
  }
  __syncthreads();

  // phase 3: out_rep (-> cat[0:192]) and tmp points (-> LDS)
  float* cat = ws + O_CAT + (size_t)i*CAT_W;
  const float* Vg  = ws + O_V;
  const float* gvv = ws + O_GV;
  for (int task = t; task < 480; task += 256) {
    if (task < 192) {
      int h = task >> 4;
      float acc = 0.f;
      #pragma unroll 4
      for (int j = 0; j < N; ++j) acc += sc[j*H+h] * Vg[j*192 + task];
      cat[task] = acc;
    } else {
      int u = task - 192;          // u = h*24 + q*3 + o
      int h = u / 24;
      float acc = 0.f;
      #pragma unroll 4
      for (int j = 0; j < N; ++j) acc += sc[j*H+h] * gvv[j*288 + u];
      tmpP[u] = acc;
    }
  }

  // phase 4: out_pair -> cat[576 + h*128 + c]
  {
    int g = t >> 7, c = t & 127;   // g selects even/odd heads
    float acc[6];
    #pragma unroll
    for (int k = 0; k < 6; ++k) acc[k] = 0.f;
    const float* zr = z + (size_t)i*N*CZ + c;
    #pragma unroll 4
    for (int j = 0; j < N; ++j) {
      float zv = zr[(size_t)j*CZ];
      #pragma unroll
      for (int k = 0; k < 6; ++k) acc[k] += sc[j*H + (k*2+g)] * zv;
    }
    #pragma unroll
    for (int k = 0; k < 6; ++k) cat[576 + (k*2+g)*128 + c] = acc[k];
  }
  __syncthreads();

  // phase 5: frame-inverse + norms
  if (t < 96) {
    int h = t >> 3, q = t & 7;
    const float* R = rot + i*9;
    float tp[3];
    #pragma unroll
    for (int p = 0; p < 3; ++p) tp[p] = tmpP[h*24 + q*3 + p] - trans[i*3 + p];
    float nrm = 1e-8f;
    #pragma unroll
    for (int o = 0; o < 3; ++o) {
      float v = R[o]*tp[0] + R[3+o]*tp[1] + R[6+o]*tp[2];
      cat[192 + h*24 + q*3 + o] = v;
      nrm += v*v;
    }
    cat[480 + h*8 + q] = sqrtf(nrm);
  }
}

// ---------------- final GEMM stage 1: partials over K chunks ----------------
// grid (32 rowTiles, 3 colTiles, 8 kChunks), 128 threads
__global__ __launch_bounds__(128) void k_out_part(
    const float* __restrict__ wo, const float* __restrict__ ws,
    float* __restrict__ part) {
  __shared__ float catT[KCH][16];        // transposed: [k][row], 16.9 KB
  int rt = blockIdx.x, ct = blockIdx.y, kc = blockIdx.z;
  int t = threadIdx.x;
  int i0 = rt * 16;
  int c  = ct * 128 + t;
  int k0 = kc * KCH;
  const float* cat = ws + O_CAT;
  for (int idx = t; idx < 16*KCH; idx += 128) {
    int r = idx / KCH, k = idx % KCH;    // consecutive idx -> consecutive k: coalesced read
    catT[k][r] = cat[(size_t)(i0 + r) * CAT_W + k0 + k];
  }
  __syncthreads();
  float acc[16];
  #pragma unroll
  for (int r = 0; r < 16; ++r) acc[r] = 0.f;
  const float* wp = wo + (size_t)k0 * 384 + c;
  #pragma unroll 4
  for (int k = 0; k < KCH; ++k) {
    float wv = wp[(size_t)k * 384];
    const float* a = catT[k];            // uniform address -> broadcast ds_read_b128 x4
    #pragma unroll
    for (int r = 0; r < 16; ++r) acc[r] += a[r] * wv;
  }
  float* dst = part + (size_t)kc * (N*CS) + (size_t)i0 * 384 + c;
  #pragma unroll
  for (int r = 0; r < 16; ++r) dst[(size_t)r * 384] = acc[r];
}

// ---------------- final GEMM stage 2: reduce partials + bias ----------------
__global__ __launch_bounds__(256) void k_out_red(
    const float* __restrict__ bo, const float* __restrict__ ws,
    float* __restrict__ out) {
  int id = blockIdx.x * 256 + threadIdx.x;   // 49152 float4 tasks
  int c4 = id % 96;
  float4 acc = ((const float4*)bo)[c4];
  const float* part = ws + O_PART;
  #pragma unroll
  for (int s = 0; s < KSPLIT; ++s) {
    float4 p = *(const float4*)(part + (size_t)s * (N*CS) + (size_t)id * 4);
    acc.x += p.x; acc.y += p.y; acc.z += p.z; acc.w += p.w;
  }
  ((float4*)out)[id] = acc;
}

extern "C" void kernel_launch(void* const* d_in, const int* in_sizes, int n_in,
                              void* d_out, int out_size, void* d_ws, size_t ws_size,
                              hipStream_t stream) {
  const float* s     = (const float*)d_in[0];
  const float* z     = (const float*)d_in[1];
  const float* rot   = (const float*)d_in[2];
  const float* trans = (const float*)d_in[3];
  const float* wq    = (const float*)d_in[4];
  const float* wk    = (const float*)d_in[5];
  const float* wv    = (const float*)d_in[6];
  const float* wqf   = (const float*)d_in[7];
  const float* wkf   = (const float*)d_in[8];
  const float* wvf   = (const float*)d_in[9];
  const float* wb    = (const float*)d_in[10];
  const float* hw    = (const float*)d_in[11];
  const float* wo    = (const float*)d_in[12];
  const float* bo    = (const float*)d_in[13];
  float* out = (float*)d_out;
  float* ws  = (float*)d_ws;

  hipLaunchKernelGGL(k_proj, dim3(512*1152/256), dim3(256), 0, stream,
                     s, wq, wk, wv, wqf, wkf, wvf, ws);
  hipLaunchKernelGGL(k_lift, dim3(512*192/256), dim3(256), 0, stream,
                     rot, trans, ws);
  hipLaunchKernelGGL(k_bias, dim3(512*512/256), dim3(256), 0, stream,
                     z, wb, ws);
  hipLaunchKernelGGL(k_attn, dim3(512), dim3(256), 0, stream,
                     z, rot, trans, hw, ws);
  hipLaunchKernelGGL(k_out_part, dim3(32, 3, KSPLIT), dim3(128), 0, stream,
                     wo, ws, ws + O_PART);
  hipLaunchKernelGGL(k_out_red, dim3(192), dim3(256), 0, stream,
                     bo, ws, out);
}